// Round 6
// baseline (588.891 us; speedup 1.0000x reference)
//
#include <hip/hip_runtime.h>
#include <hip/hip_bf16.h>

#define Bb 8
#define Tt 512
#define Cc 32
#define Dd 128
#define SCALE 0.08838834764831845f
#define SROW2 264  // S chunk row stride in bf16 elems (256 + 8 pad)

typedef unsigned int u32;
typedef __hip_bfloat16 bf16;
typedef __attribute__((ext_vector_type(8))) short short8;
typedef __attribute__((ext_vector_type(4))) short short4v;
typedef __attribute__((ext_vector_type(4))) float floatx4;

__device__ __forceinline__ short f2bf(float f) {
    __hip_bfloat16 h = __float2bfloat16(f);
    return *(short*)&h;
}
__device__ __forceinline__ float bf2f(short s) {
    return __uint_as_float(((u32)(unsigned short)s) << 16);
}

// ---------------- Kernel 0: W f32 -> bf16 ----------------
__global__ __launch_bounds__(256)
void k_wconv(const float* __restrict__ wq, const float* __restrict__ wk,
             const float* __restrict__ wv, short* __restrict__ Wb)
{
    int g = blockIdx.x * 256 + threadIdx.x;
    int mat = g >> 14, rem = g & 16383;
    const float* src = (mat == 0) ? wq : (mat == 1) ? wk : wv;
    Wb[g] = f2bf(src[rem]);
}

// ---------------- Kernel 1: gather + QKV (MFMA) + rotation + q*SCALE -------
// r0-exact single-pass version: block = 64 consecutive (b,t,c) rows =
// 2 tokens x 32 channels (gather stays in two 16KB token rows, L1-resident);
// all 3 matrices per pass (2 barriers/block).
__global__ __launch_bounds__(256)
void k_qkvm(const float* __restrict__ x, const int* __restrict__ xm,
            const int* __restrict__ pos, const float* __restrict__ pe,
            const int* __restrict__ imp, const int* __restrict__ idxc,
            const short* __restrict__ Wb,
            const float* __restrict__ bq, const float* __restrict__ bk,
            const float* __restrict__ bv,
            short* __restrict__ qb, short* __restrict__ kb, short* __restrict__ vb)
{
    const int R0  = blockIdx.x * 64;
    const int b   = R0 >> 14;
    const int t0  = (R0 >> 5) & 511;
    const int tid = threadIdx.x;
    const int w    = tid >> 6;
    const int lane = tid & 63;
    const int quad = lane >> 4;
    const int m    = lane & 15;

    __shared__ short xg[64 * 136];
    __shared__ short ot[64 * 392];

#pragma unroll
    for (int i = 0; i < 8; ++i) {
        int u   = tid + i * 256;
        int row = u >> 5, seg = u & 31;
        int R   = R0 + row;
        int idx = xm[R] ? imp[R >> 5] : idxc[R];
        float4 v = *(const float4*)(x + ((long)(R >> 5) * Cc + idx) * Dd + seg * 4);
        short4v s = {f2bf(v.x), f2bf(v.y), f2bf(v.z), f2bf(v.w)};
        *(short4v*)&xg[row * 136 + seg * 4] = s;
    }

    short8 wf[6][4];
    float  bias_v[6];
#pragma unroll
    for (int mat = 0; mat < 3; ++mat) {
        const float* bp = (mat == 0) ? bq : (mat == 1) ? bk : bv;
#pragma unroll
        for (int h = 0; h < 2; ++h) {
            int sl = mat * 2 + h;
            int ct = h * 4 + w;
            bias_v[sl] = bp[ct * 16 + m];
#pragma unroll
            for (int kk = 0; kk < 4; ++kk)
                wf[sl][kk] = *(const short8*)(Wb + ((long)mat * 128 + ct * 16 + m) * 128
                                              + kk * 32 + quad * 8);
        }
    }
    __syncthreads();

    for (int rt = 0; rt < 4; ++rt) {
        short8 af[4];
#pragma unroll
        for (int kk = 0; kk < 4; ++kk)
            af[kk] = *(const short8*)&xg[(rt * 16 + m) * 136 + kk * 32 + quad * 8];

        floatx4 acc[6];
#pragma unroll
        for (int sl = 0; sl < 6; ++sl) acc[sl] = (floatx4){0.f, 0.f, 0.f, 0.f};
#pragma unroll
        for (int kk = 0; kk < 4; ++kk)
#pragma unroll
            for (int sl = 0; sl < 6; ++sl)
                acc[sl] = __builtin_amdgcn_mfma_f32_16x16x32_bf16(af[kk], wf[sl][kk], acc[sl], 0, 0, 0);

        int po[4];
#pragma unroll
        for (int r = 0; r < 4; ++r) po[r] = pos[R0 + rt * 16 + quad * 4 + r];

#pragma unroll
        for (int sl = 0; sl < 6; ++sl) {
            int mat = sl >> 1;
            int ct  = (sl & 1) * 4 + w;
            int d   = ct * 16 + m;
#pragma unroll
            for (int r = 0; r < 4; ++r) {
                float v = acc[sl][r] + bias_v[sl];
                float p = __shfl_xor(v, 1, 64);
                if (mat < 2) {
                    const float* rp = pe + ((long)po[r] * (Dd / 2) + (d >> 1)) * 2;
                    float r0 = rp[0], r1 = rp[1];
                    v = (d & 1) ? fmaf(p, r1, v * r0) : fmaf(v, r0, -(p * r1));
                    if (mat == 0) v *= SCALE;
                }
                ot[(rt * 16 + quad * 4 + r) * 392 + mat * 128 + d] = f2bf(v);
            }
        }
    }
    __syncthreads();

    short* const mats[3] = {qb, kb, vb};
#pragma unroll
    for (int mat = 0; mat < 3; ++mat) {
        short* dst = mats[mat];
#pragma unroll
        for (int i = 0; i < 4; ++i) {
            int g = tid + i * 256;
            int n = g >> 4, off = (g & 15) * 8;
            int c = n & 31, tl = n >> 5;
            *(short8*)(dst + (((long)(b * Cc + c) * Tt) + t0 + tl) * Dd + off) =
                *(const short8*)&ot[n * 392 + mat * 128 + off];
        }
    }
}

// ---------------- Kernel 1b: V transpose + wk fold ----------------
// r0 structure + XOR swizzle on the 8-elem column groups (bijective per
// row): fixes the 8-way transpose-read bank conflict (r5-proven).
__global__ __launch_bounds__(256)
void k_vt(const short* __restrict__ vb, const int* __restrict__ xm,
          short* __restrict__ vt)
{
    const int head = blockIdx.y;
    const int b    = head >> 5;
    const int c    = head & 31;
    const int t0   = blockIdx.x * 64;
    const int tid  = threadIdx.x;

    __shared__ short tile[64 * 136];
    __shared__ float wks[64];

    if (tid < 64)
        wks[tid] = xm[((long)b * Tt + t0 + tid) * Cc + c] ? (1.0f / Tt) : 1.0f;

    const short* src = vb + ((long)head * Tt + t0) * Dd;
#pragma unroll
    for (int i = 0; i < 4; ++i) {
        int u = tid + i * 256;
        int row = u >> 4, col8 = u & 15;
        int c8 = col8 ^ ((row >> 3) & 7);          // swizzled 16B slot
        *(short8*)&tile[row * 136 + c8 * 8] = *(const short8*)(src + row * Dd + col8 * 8);
    }
    __syncthreads();

    short* dst = vt + (long)head * Dd * Tt + t0;
#pragma unroll
    for (int i = 0; i < 4; ++i) {
        int u = tid + i * 256;
        int d = u >> 3, t8 = (u & 7) * 8;
        int key = u & 7;                           // == ((t8+j)>>3)&7 for j<8
        int cs = ((d >> 3) ^ key) * 8 + (d & 7);
        short8 v;
#pragma unroll
        for (int j = 0; j < 8; ++j)
            v[j] = f2bf(bf2f(tile[(t8 + j) * 136 + cs]) * wks[t8 + j]);
        *(short8*)(dst + (long)d * Tt + t8) = v;
    }
}

// ---------------- Kernel 2: TQ=64 online-softmax attention + fused LN ------
// Same grid/traffic as the proven r1 kernel (TQ=64, XCD grouping, 2MB L2
// window, FETCH ~100MB) but the 512 score columns are processed in TWO
// 256-col chunks with online softmax (running m,l per row; oa rescaled by
// exp(m_old-m_new) between chunks). S shrinks 66.6->33.8 KB, total LDS
// ~39 KB -> 4 blocks/CU (32 waves, occupancy cap) at IDENTICAL traffic --
// the clean version of r2's occupancy hypothesis without its 2x re-reads.
__global__ __launch_bounds__(512, 8)
void k_attn(const short* __restrict__ qb, const short* __restrict__ kbp,
            const short* __restrict__ vtp, const float* __restrict__ x,
            const int* __restrict__ pm,
            const float* __restrict__ lsg, const float* __restrict__ lng,
            const float* __restrict__ lnb, float* __restrict__ out)
{
    const int l    = blockIdx.y * 256 + blockIdx.x;
    const int xcd  = l & 7;
    const int sws  = l >> 3;
    const int hh   = sws & 7;
    const int tl   = (sws >> 3) & 7;
    const int gg   = sws >> 6;
    const int head = xcd + ((gg * 8 + hh) << 3);   // head % 8 == xcd
    const int b    = head >> 5;
    const int c    = head & 31;
    const int qt0  = tl * 64;
    const int tid  = threadIdx.x;
    const int w    = tid >> 6;            // 0..7
    const int lane = tid & 63;
    const int quad = lane >> 4;
    const int m    = lane & 15;

    __shared__ short S[64 * SROW2];       // 33.8 KB
    __shared__ u32   pkbits[16];
    __shared__ float rlS[64];
    __shared__ float alS[64];
    __shared__ float ps1[8][64];
    __shared__ float ps2[8][64];
    __shared__ float mrs[64][2];

    // ---- p_mask bits for all 512 tokens of this head ----
    {
        bool v = pm[((long)b * Tt + tid) * Cc + c] != 0;
        unsigned long long bal = __ballot(v);
        if (lane == 0) {
            pkbits[w * 2]     = (u32)bal;
            pkbits[w * 2 + 1] = (u32)(bal >> 32);
        }
    }

    // ---- Q A-frags: 4 q-tiles (q pre-scaled by SCALE) ----
    short8 qf[4][4];
#pragma unroll
    for (int qt = 0; qt < 4; ++qt)
#pragma unroll
        for (int kk = 0; kk < 4; ++kk)
            qf[qt][kk] = *(const short8*)(qb + ((long)head * Tt + qt0 + qt * 16 + m) * Dd
                                          + kk * 32 + quad * 8);
    __syncthreads();

    const short* vbase = vtp + (long)head * Dd * Tt + ((long)(w * 16 + m)) * Tt + quad * 8;

    floatx4 oa[4];
#pragma unroll
    for (int qt = 0; qt < 4; ++qt) oa[qt] = (floatx4){0.f, 0.f, 0.f, 0.f};

    float m_run = -1e30f, l_run = 0.f;    // online softmax state (row tid>>3)

    for (int hk = 0; hk < 2; ++hk) {
        // ---- QK^T chunk: cols hk*256 .. +255 ----
        for (int ch = 0; ch < 2; ++ch) {
            int ktl = ch * 128 + w * 16 + m;       // local col 0..255
            int kt  = hk * 256 + ktl;
            const short* kp = kbp + ((long)head * Tt + kt) * Dd + quad * 8;
            floatx4 sc[4];
#pragma unroll
            for (int qt = 0; qt < 4; ++qt) sc[qt] = (floatx4){0.f, 0.f, 0.f, 0.f};
#pragma unroll
            for (int kk = 0; kk < 4; ++kk) {
                short8 bk = *(const short8*)(kp + kk * 32);
#pragma unroll
                for (int qt = 0; qt < 4; ++qt)
                    sc[qt] = __builtin_amdgcn_mfma_f32_16x16x32_bf16(qf[qt][kk], bk, sc[qt], 0, 0, 0);
            }
            bool masked = (pkbits[kt >> 5] >> (kt & 31)) & 1;
#pragma unroll
            for (int qt = 0; qt < 4; ++qt)
#pragma unroll
                for (int r = 0; r < 4; ++r)
                    S[(qt * 16 + quad * 4 + r) * SROW2 + ktl] = f2bf(masked ? -1e30f : sc[qt][r]);
        }
        __syncthreads();

        // ---- online softmax partial: row qi = tid>>3, 8 parts of 8x4 ----
        {
            int qi = tid >> 3, part = tid & 7;
            short* rowp = &S[qi * SROW2 + part * 8];
            short8 sv[4];
#pragma unroll
            for (int j = 0; j < 4; ++j) sv[j] = *(short8*)&rowp[j * 64];
            float mx = -1e30f;
#pragma unroll
            for (int j = 0; j < 4; ++j)
#pragma unroll
                for (int e = 0; e < 8; ++e) mx = fmaxf(mx, bf2f(sv[j][e]));
            mx = fmaxf(mx, __shfl_xor(mx, 1, 64));
            mx = fmaxf(mx, __shfl_xor(mx, 2, 64));
            mx = fmaxf(mx, __shfl_xor(mx, 4, 64));
            float m_new = fmaxf(m_run, mx);
            float lsum = 0.f;
#pragma unroll
            for (int j = 0; j < 4; ++j)
#pragma unroll
                for (int e = 0; e < 8; ++e) {
                    float s = bf2f(sv[j][e]);
                    float ex = (s <= -1e29f) ? 0.f : __expf(s - m_new);
                    sv[j][e] = f2bf(ex);
                    lsum += ex;
                }
#pragma unroll
            for (int j = 0; j < 4; ++j) *(short8*)&rowp[j * 64] = sv[j];
            lsum += __shfl_xor(lsum, 1, 64);
            lsum += __shfl_xor(lsum, 2, 64);
            lsum += __shfl_xor(lsum, 4, 64);
            float al = __expf(m_run - m_new);      // ==1 when m unchanged
            l_run = l_run * al + lsum;
            m_run = m_new;
            if (part == 0) {
                alS[qi] = al;
                if (hk == 1) {
                    int t = qt0 + qi;
                    bool qmask = (pkbits[t >> 5] >> (t & 31)) & 1;
                    rlS[qi] = (l_run > 0.f && !qmask) ? 1.0f / l_run : 0.f;
                }
            }
        }
        __syncthreads();

        // ---- PV chunk: rescale oa by this chunk's alpha, then accumulate --
#pragma unroll
        for (int qt = 0; qt < 4; ++qt)
#pragma unroll
            for (int r = 0; r < 4; ++r)
                oa[qt][r] *= alS[qt * 16 + quad * 4 + r];
        for (int kv = 0; kv < 8; ++kv) {
            short8 bv = *(const short8*)(vbase + (hk * 8 + kv) * 32);
#pragma unroll
            for (int qt = 0; qt < 4; ++qt) {
                short8 ap = *(const short8*)&S[(qt * 16 + m) * SROW2 + kv * 32 + quad * 8];
                oa[qt] = __builtin_amdgcn_mfma_f32_16x16x32_bf16(ap, bv, oa[qt], 0, 0, 0);
            }
        }
        __syncthreads();   // S reused next chunk; rlS ready after hk==1
    }

    // ---- epilogue: y = x + ls*(O*rl); LN over d=128 (8-wave partials) ----
    const int d = w * 16 + m;
    const float lg = lsg[d];
    float yv[4][4];
#pragma unroll
    for (int qt = 0; qt < 4; ++qt)
#pragma unroll
        for (int r = 0; r < 4; ++r) {
            int row = qt * 16 + quad * 4 + r;
            int t = qt0 + row;
            float val = oa[qt][r] * rlS[row];
            float y = x[(((long)b * Tt + t) * Cc + c) * Dd + d] + lg * val;
            yv[qt][r] = y;
        }
#pragma unroll
    for (int qt = 0; qt < 4; ++qt)
#pragma unroll
        for (int r = 0; r < 4; ++r) {
            float a = yv[qt][r], bb = yv[qt][r] * yv[qt][r];
            a += __shfl_xor(a, 1, 64); bb += __shfl_xor(bb, 1, 64);
            a += __shfl_xor(a, 2, 64); bb += __shfl_xor(bb, 2, 64);
            a += __shfl_xor(a, 4, 64); bb += __shfl_xor(bb, 4, 64);
            a += __shfl_xor(a, 8, 64); bb += __shfl_xor(bb, 8, 64);
            if (m == 0) {
                ps1[w][qt * 16 + quad * 4 + r] = a;
                ps2[w][qt * 16 + quad * 4 + r] = bb;
            }
        }
    __syncthreads();
    if (tid < 64) {
        float a = 0.f, bb = 0.f;
#pragma unroll
        for (int wv = 0; wv < 8; ++wv) { a += ps1[wv][tid]; bb += ps2[wv][tid]; }
        float mean = a * (1.0f / Dd);
        float var  = bb * (1.0f / Dd) - mean * mean;
        mrs[tid][0] = mean;
        mrs[tid][1] = rsqrtf(var + 1e-5f);
    }
    __syncthreads();

    const float g = lng[d], be = lnb[d];
#pragma unroll
    for (int qt = 0; qt < 4; ++qt)
#pragma unroll
        for (int r = 0; r < 4; ++r) {
            int row = qt * 16 + quad * 4 + r;
            int t = qt0 + row;
            out[(((long)b * Tt + t) * Cc + c) * Dd + d] =
                (yv[qt][r] - mrs[row][0]) * mrs[row][1] * g + be;
        }
}

extern "C" void kernel_launch(void* const* d_in, const int* in_sizes, int n_in,
                              void* d_out, int out_size, void* d_ws, size_t ws_size,
                              hipStream_t stream) {
    const float* x    = (const float*)d_in[0];
    const int* xmask  = (const int*)d_in[1];
    const int* pmask  = (const int*)d_in[2];
    const int* pos    = (const int*)d_in[3];
    const float* pe   = (const float*)d_in[4];
    const int* imp    = (const int*)d_in[5];
    const int* idxc   = (const int*)d_in[6];
    const float* wq_w = (const float*)d_in[7];
    const float* wq_b = (const float*)d_in[8];
    const float* wk_w = (const float*)d_in[9];
    const float* wk_b = (const float*)d_in[10];
    const float* wv_w = (const float*)d_in[11];
    const float* wv_b = (const float*)d_in[12];
    const float* lsg  = (const float*)d_in[13];
    const float* lng  = (const float*)d_in[14];
    const float* lnb  = (const float*)d_in[15];
    float* out = (float*)d_out;

    size_t n = (size_t)Bb * Cc * Tt * Dd;
    short* qb = (short*)d_ws;
    short* kb = qb + n;
    short* vb = kb + n;
    short* vt = vb + n;
    short* Wb = vt + n;

    k_wconv<<<dim3(3 * Dd * Dd / 256), dim3(256), 0, stream>>>(wq_w, wk_w, wv_w, Wb);
    k_qkvm<<<dim3(Bb * Tt * Cc / 64), dim3(256), 0, stream>>>(
        x, xmask, pos, pe, imp, idxc, Wb, wq_b, wk_b, wv_b, qb, kb, vb);
    k_vt<<<dim3(Tt / 64, Bb * Cc), dim3(256), 0, stream>>>(vb, xmask, vt);
    k_attn<<<dim3(256, 8), dim3(512), 0, stream>>>(
        qb, kb, vt, x, pmask, lsg, lng, lnb, out);
}

// Round 7
// 354.968 us; speedup vs baseline: 1.6590x; 1.6590x over previous
//
#include <hip/hip_runtime.h>
#include <hip/hip_bf16.h>

#define Bb 8
#define Tt 512
#define Cc 32
#define Dd 128
#define SCALE 0.08838834764831845f
#define SROW 520  // S row stride in bf16 elems (512 + 8 pad, 16B-aligned)
#define OROW 264  // k_qkvm ot row stride (Q 128 + K 128 + 8 pad)

typedef unsigned int u32;
typedef __hip_bfloat16 bf16;
typedef __attribute__((ext_vector_type(8))) short short8;
typedef __attribute__((ext_vector_type(4))) short short4v;
typedef __attribute__((ext_vector_type(4))) float floatx4;

__device__ __forceinline__ short f2bf(float f) {
    __hip_bfloat16 h = __float2bfloat16(f);
    return *(short*)&h;
}
__device__ __forceinline__ float bf2f(short s) {
    return __uint_as_float(((u32)(unsigned short)s) << 16);
}

// ---------------- Kernel 0: W f32 -> bf16 ----------------
__global__ __launch_bounds__(256)
void k_wconv(const float* __restrict__ wq, const float* __restrict__ wk,
             const float* __restrict__ wv, short* __restrict__ Wb)
{
    int g = blockIdx.x * 256 + threadIdx.x;
    int mat = g >> 14, rem = g & 16383;
    const float* src = (mat == 0) ? wq : (mat == 1) ? wk : wv;
    Wb[g] = f2bf(src[rem]);
}

// ---------------- Kernel 1: gather + Q,K (MFMA) + rotation + q*SCALE -------
// r0-proven block shape (64 rows = 2 tokens x 32 channels, L1-resident
// gather). V third removed (now computed in k_v): MFMA 24->16/block,
// ot 392->264 wide -> LDS 51.2 KB (3 blocks/CU), writes -32MB.
__global__ __launch_bounds__(256)
void k_qkvm(const float* __restrict__ x, const int* __restrict__ xm,
            const int* __restrict__ pos, const float* __restrict__ pe,
            const int* __restrict__ imp, const int* __restrict__ idxc,
            const short* __restrict__ Wb,
            const float* __restrict__ bq, const float* __restrict__ bk,
            short* __restrict__ qb, short* __restrict__ kb)
{
    const int R0  = blockIdx.x * 64;
    const int b   = R0 >> 14;
    const int t0  = (R0 >> 5) & 511;
    const int tid = threadIdx.x;
    const int w    = tid >> 6;
    const int lane = tid & 63;
    const int quad = lane >> 4;
    const int m    = lane & 15;

    __shared__ short xg[64 * 136];
    __shared__ short ot[64 * OROW];

#pragma unroll
    for (int i = 0; i < 8; ++i) {
        int u   = tid + i * 256;
        int row = u >> 5, seg = u & 31;
        int R   = R0 + row;
        int idx = xm[R] ? imp[R >> 5] : idxc[R];
        float4 v = *(const float4*)(x + ((long)(R >> 5) * Cc + idx) * Dd + seg * 4);
        short4v s = {f2bf(v.x), f2bf(v.y), f2bf(v.z), f2bf(v.w)};
        *(short4v*)&xg[row * 136 + seg * 4] = s;
    }

    short8 wf[4][4];
    float  bias_v[4];
#pragma unroll
    for (int mat = 0; mat < 2; ++mat) {
        const float* bp = (mat == 0) ? bq : bk;
#pragma unroll
        for (int h = 0; h < 2; ++h) {
            int sl = mat * 2 + h;
            int ct = h * 4 + w;
            bias_v[sl] = bp[ct * 16 + m];
#pragma unroll
            for (int kk = 0; kk < 4; ++kk)
                wf[sl][kk] = *(const short8*)(Wb + ((long)mat * 128 + ct * 16 + m) * 128
                                              + kk * 32 + quad * 8);
        }
    }
    __syncthreads();

    for (int rt = 0; rt < 4; ++rt) {
        short8 af[4];
#pragma unroll
        for (int kk = 0; kk < 4; ++kk)
            af[kk] = *(const short8*)&xg[(rt * 16 + m) * 136 + kk * 32 + quad * 8];

        floatx4 acc[4];
#pragma unroll
        for (int sl = 0; sl < 4; ++sl) acc[sl] = (floatx4){0.f, 0.f, 0.f, 0.f};
#pragma unroll
        for (int kk = 0; kk < 4; ++kk)
#pragma unroll
            for (int sl = 0; sl < 4; ++sl)
                acc[sl] = __builtin_amdgcn_mfma_f32_16x16x32_bf16(af[kk], wf[sl][kk], acc[sl], 0, 0, 0);

        int po[4];
#pragma unroll
        for (int r = 0; r < 4; ++r) po[r] = pos[R0 + rt * 16 + quad * 4 + r];

#pragma unroll
        for (int sl = 0; sl < 4; ++sl) {
            int mat = sl >> 1;
            int ct  = (sl & 1) * 4 + w;
            int d   = ct * 16 + m;
#pragma unroll
            for (int r = 0; r < 4; ++r) {
                float v = acc[sl][r] + bias_v[sl];
                float p = __shfl_xor(v, 1, 64);
                const float* rp = pe + ((long)po[r] * (Dd / 2) + (d >> 1)) * 2;
                float r0 = rp[0], r1 = rp[1];
                v = (d & 1) ? fmaf(p, r1, v * r0) : fmaf(v, r0, -(p * r1));
                if (mat == 0) v *= SCALE;
                ot[(rt * 16 + quad * 4 + r) * OROW + mat * 128 + d] = f2bf(v);
            }
        }
    }
    __syncthreads();

    short* const mats[2] = {qb, kb};
#pragma unroll
    for (int mat = 0; mat < 2; ++mat) {
        short* dst = mats[mat];
#pragma unroll
        for (int i = 0; i < 4; ++i) {
            int g = tid + i * 256;
            int n = g >> 4, off = (g & 15) * 8;
            int c = n & 31, tl = n >> 5;
            *(short8*)(dst + (((long)(b * Cc + c) * Tt) + t0 + tl) * Dd + off) =
                *(const short8*)&ot[n * OROW + mat * 128 + off];
        }
    }
}

// ---------------- Kernel 1b: V compute + transpose + wk fold ---------------
// Replaces k_vt: computes V = x.Wv^T + b directly from (re-gathered,
// L3-resident) x for this (head, 64-token) tile -- kills the 64MB vb
// round-trip. Weight wks folded into the f32 accumulator. Output goes
// through the r5-proven XOR-swizzled LDS transpose (conflict-free).
__global__ __launch_bounds__(256)
void k_v(const float* __restrict__ x, const int* __restrict__ xm,
         const int* __restrict__ imp, const int* __restrict__ idxc,
         const short* __restrict__ Wb, const float* __restrict__ bvp,
         short* __restrict__ vt)
{
    const int head = blockIdx.y;          // b*C + c
    const int b    = head >> 5;
    const int c    = head & 31;
    const int t0   = blockIdx.x * 64;
    const int tid  = threadIdx.x;
    const int w    = tid >> 6;
    const int lane = tid & 63;
    const int quad = lane >> 4;
    const int m    = lane & 15;

    __shared__ short xg[64 * 136];
    __shared__ short tile[64 * 136];
    __shared__ float wks[64];

    // gather 64 token-rows of channel c (x is L3-hot from k_qkvm)
#pragma unroll
    for (int i = 0; i < 8; ++i) {
        int u   = tid + i * 256;
        int row = u >> 5, seg = u & 31;
        long tr = (long)b * Tt + t0 + row;
        long R  = tr * Cc + c;
        int xmv = xm[R];
        int idx = xmv ? imp[tr] : idxc[R];
        float4 v = *(const float4*)(x + (tr * Cc + idx) * Dd + seg * 4);
        short4v s = {f2bf(v.x), f2bf(v.y), f2bf(v.z), f2bf(v.w)};
        *(short4v*)&xg[row * 136 + seg * 4] = s;
        if (seg == 0) wks[row] = xmv ? (1.0f / Tt) : 1.0f;
    }

    short8 wf[2][4];
    float  bias_v[2];
#pragma unroll
    for (int h = 0; h < 2; ++h) {
        int ct = h * 4 + w;
        bias_v[h] = bvp[ct * 16 + m];
#pragma unroll
        for (int kk = 0; kk < 4; ++kk)
            wf[h][kk] = *(const short8*)(Wb + ((long)2 * 128 + ct * 16 + m) * 128
                                         + kk * 32 + quad * 8);
    }
    __syncthreads();

#pragma unroll
    for (int rt = 0; rt < 4; ++rt) {
        short8 af[4];
#pragma unroll
        for (int kk = 0; kk < 4; ++kk)
            af[kk] = *(const short8*)&xg[(rt * 16 + m) * 136 + kk * 32 + quad * 8];

        floatx4 acc[2];
        acc[0] = (floatx4){0.f, 0.f, 0.f, 0.f};
        acc[1] = (floatx4){0.f, 0.f, 0.f, 0.f};
#pragma unroll
        for (int kk = 0; kk < 4; ++kk)
#pragma unroll
            for (int h = 0; h < 2; ++h)
                acc[h] = __builtin_amdgcn_mfma_f32_16x16x32_bf16(af[kk], wf[h][kk], acc[h], 0, 0, 0);

        // store into swizzled transpose tile (wks folded in f32)
#pragma unroll
        for (int h = 0; h < 2; ++h) {
            int ct = h * 4 + w;
            int d  = ct * 16 + m;
#pragma unroll
            for (int r = 0; r < 4; ++r) {
                int row = rt * 16 + quad * 4 + r;
                float v = (acc[h][r] + bias_v[h]) * wks[row];
                int c8 = (d >> 3) ^ ((row >> 3) & 7);    // swizzled 16B slot
                tile[row * 136 + c8 * 8 + (d & 7)] = f2bf(v);
            }
        }
    }
    __syncthreads();

    // transpose writeout (r5-proven conflict-free pattern)
    short* dst = vt + (long)head * Dd * Tt + t0;
#pragma unroll
    for (int i = 0; i < 4; ++i) {
        int u = tid + i * 256;
        int d = u >> 3, t8 = (u & 7) * 8;
        int key = u & 7;                           // == ((t8+j)>>3)&7 for j<8
        int cs = ((d >> 3) ^ key) * 8 + (d & 7);
        short8 v;
#pragma unroll
        for (int j = 0; j < 8; ++j)
            v[j] = tile[(t8 + j) * 136 + cs];
        *(short8*)(dst + (long)d * Tt + t8) = v;
    }
}

// ---------------- Kernel 2: TQ=64, 8-wave MFMA attention + fused LN --------
// r5-exact (measured 137-141 us across four rounds): TQ=64, 2 blocks/CU,
// XCD grouping (8 heads x 8 q-tiles per XCD -> 2MB L2 window, FETCH ~100MB),
// conflict-free interleaved softmax. Occupancy attacks closed: r2 (TQ=32)
// doubled traffic; r6 (online-softmax @ 8 waves/EU) forced VGPR 32 -> 600MB
// scratch spill. This structure needs ~100 VGPR; 2 blocks/CU is its design
// point.
__global__ __launch_bounds__(512, 4)
void k_attn(const short* __restrict__ qb, const short* __restrict__ kbp,
            const short* __restrict__ vtp, const float* __restrict__ x,
            const int* __restrict__ pm,
            const float* __restrict__ lsg, const float* __restrict__ lng,
            const float* __restrict__ lnb, float* __restrict__ out)
{
    const int l    = blockIdx.y * 256 + blockIdx.x;
    const int xcd  = l & 7;
    const int sws  = l >> 3;
    const int hh   = sws & 7;
    const int tl   = (sws >> 3) & 7;
    const int gg   = sws >> 6;
    const int head = xcd + ((gg * 8 + hh) << 3);   // head % 8 == xcd
    const int b    = head >> 5;
    const int c    = head & 31;
    const int qt0  = tl * 64;
    const int tid  = threadIdx.x;
    const int w    = tid >> 6;            // 0..7
    const int lane = tid & 63;
    const int quad = lane >> 4;
    const int m    = lane & 15;

    __shared__ short S[64 * SROW];        // 66.6 KB
    __shared__ u32   pkbits[16];
    __shared__ float rlS[64];
    __shared__ float ps1[8][64];
    __shared__ float ps2[8][64];
    __shared__ float mrs[64][2];

    // ---- p_mask bits for all 512 tokens of this head ----
    {
        bool v = pm[((long)b * Tt + tid) * Cc + c] != 0;
        unsigned long long bal = __ballot(v);
        if (lane == 0) {
            pkbits[w * 2]     = (u32)bal;
            pkbits[w * 2 + 1] = (u32)(bal >> 32);
        }
    }

    // ---- Q A-frags: 4 q-tiles (q pre-scaled by SCALE) ----
    short8 qf[4][4];
#pragma unroll
    for (int qt = 0; qt < 4; ++qt)
#pragma unroll
        for (int kk = 0; kk < 4; ++kk)
            qf[qt][kk] = *(const short8*)(qb + ((long)head * Tt + qt0 + qt * 16 + m) * Dd
                                          + kk * 32 + quad * 8);
    __syncthreads();

    // ---- QK^T: each wave owns k-strip w*16 within 128-chunks ----
    for (int ch = 0; ch < 4; ++ch) {
        int kt = ch * 128 + w * 16 + m;
        const short* kp = kbp + ((long)head * Tt + kt) * Dd + quad * 8;
        floatx4 sc[4];
#pragma unroll
        for (int qt = 0; qt < 4; ++qt) sc[qt] = (floatx4){0.f, 0.f, 0.f, 0.f};
#pragma unroll
        for (int kk = 0; kk < 4; ++kk) {
            short8 bk = *(const short8*)(kp + kk * 32);
#pragma unroll
            for (int qt = 0; qt < 4; ++qt)
                sc[qt] = __builtin_amdgcn_mfma_f32_16x16x32_bf16(qf[qt][kk], bk, sc[qt], 0, 0, 0);
        }
        bool masked = (pkbits[kt >> 5] >> (kt & 31)) & 1;
#pragma unroll
        for (int qt = 0; qt < 4; ++qt)
#pragma unroll
            for (int r = 0; r < 4; ++r)
                S[(qt * 16 + quad * 4 + r) * SROW + kt] = f2bf(masked ? -1e30f : sc[qt][r]);
    }
    __syncthreads();

    // ---- softmax: row qi = tid>>3; lane covers cols part*8 + j*64 + e ----
    // (interleaved 8-elem blocks: 128B part-stride was an 8-way bank
    //  conflict; this mapping spreads each phase over all 32 banks.)
    {
        int qi = tid >> 3, part = tid & 7;
        short* rowp = &S[qi * SROW + part * 8];
        short8 sv[8];
#pragma unroll
        for (int j = 0; j < 8; ++j) sv[j] = *(short8*)&rowp[j * 64];
        float mx = -1e30f;
#pragma unroll
        for (int j = 0; j < 8; ++j)
#pragma unroll
            for (int e = 0; e < 8; ++e) mx = fmaxf(mx, bf2f(sv[j][e]));
        mx = fmaxf(mx, __shfl_xor(mx, 1, 64));
        mx = fmaxf(mx, __shfl_xor(mx, 2, 64));
        mx = fmaxf(mx, __shfl_xor(mx, 4, 64));
        float lsum = 0.f;
#pragma unroll
        for (int j = 0; j < 8; ++j)
#pragma unroll
            for (int e = 0; e < 8; ++e) {
                float s = bf2f(sv[j][e]);
                float ex = (s <= -1e29f) ? 0.f : __expf(s - mx);
                sv[j][e] = f2bf(ex);
                lsum += ex;
            }
#pragma unroll
        for (int j = 0; j < 8; ++j) *(short8*)&rowp[j * 64] = sv[j];
        lsum += __shfl_xor(lsum, 1, 64);
        lsum += __shfl_xor(lsum, 2, 64);
        lsum += __shfl_xor(lsum, 4, 64);
        if (part == 0) {
            int t = qt0 + qi;
            bool qmask = (pkbits[t >> 5] >> (t & 31)) & 1;
            rlS[qi] = (lsum > 0.f && !qmask) ? 1.0f / lsum : 0.f;
        }
    }
    __syncthreads();

    // ---- PV: wave owns d-strip w*16..+15; B-frags from Vt global ----
    floatx4 oa[4];
#pragma unroll
    for (int qt = 0; qt < 4; ++qt) oa[qt] = (floatx4){0.f, 0.f, 0.f, 0.f};

    const short* vbase = vtp + (long)head * Dd * Tt + ((long)(w * 16 + m)) * Tt + quad * 8;
    for (int kv = 0; kv < 16; ++kv) {
        short8 bv = *(const short8*)(vbase + kv * 32);
#pragma unroll
        for (int qt = 0; qt < 4; ++qt) {
            short8 ap = *(const short8*)&S[(qt * 16 + m) * SROW + kv * 32 + quad * 8];
            oa[qt] = __builtin_amdgcn_mfma_f32_16x16x32_bf16(ap, bv, oa[qt], 0, 0, 0);
        }
    }

    // ---- epilogue: y = x + ls*(O*rl); LN over d=128 (8-wave partials) ----
    const int d = w * 16 + m;
    const float lg = lsg[d];
    float yv[4][4];
    float s1[4][4], s2[4][4];
#pragma unroll
    for (int qt = 0; qt < 4; ++qt)
#pragma unroll
        for (int r = 0; r < 4; ++r) {
            int row = qt * 16 + quad * 4 + r;
            int t = qt0 + row;
            float val = oa[qt][r] * rlS[row];
            float y = x[(((long)b * Tt + t) * Cc + c) * Dd + d] + lg * val;
            yv[qt][r] = y;
            s1[qt][r] = y;
            s2[qt][r] = y * y;
        }
#pragma unroll
    for (int qt = 0; qt < 4; ++qt)
#pragma unroll
        for (int r = 0; r < 4; ++r) {
            float a = s1[qt][r], bb = s2[qt][r];
            a += __shfl_xor(a, 1, 64); bb += __shfl_xor(bb, 1, 64);
            a += __shfl_xor(a, 2, 64); bb += __shfl_xor(bb, 2, 64);
            a += __shfl_xor(a, 4, 64); bb += __shfl_xor(bb, 4, 64);
            a += __shfl_xor(a, 8, 64); bb += __shfl_xor(bb, 8, 64);
            if (m == 0) {
                ps1[w][qt * 16 + quad * 4 + r] = a;
                ps2[w][qt * 16 + quad * 4 + r] = bb;
            }
        }
    __syncthreads();
    if (tid < 64) {
        float a = 0.f, bb = 0.f;
#pragma unroll
        for (int wv = 0; wv < 8; ++wv) { a += ps1[wv][tid]; bb += ps2[wv][tid]; }
        float mean = a * (1.0f / Dd);
        float var  = bb * (1.0f / Dd) - mean * mean;
        mrs[tid][0] = mean;
        mrs[tid][1] = rsqrtf(var + 1e-5f);
    }
    __syncthreads();

    const float g = lng[d], be = lnb[d];
#pragma unroll
    for (int qt = 0; qt < 4; ++qt)
#pragma unroll
        for (int r = 0; r < 4; ++r) {
            int row = qt * 16 + quad * 4 + r;
            int t = qt0 + row;
            out[(((long)b * Tt + t) * Cc + c) * Dd + d] =
                (yv[qt][r] - mrs[row][0]) * mrs[row][1] * g + be;
        }
}

extern "C" void kernel_launch(void* const* d_in, const int* in_sizes, int n_in,
                              void* d_out, int out_size, void* d_ws, size_t ws_size,
                              hipStream_t stream) {
    const float* x    = (const float*)d_in[0];
    const int* xmask  = (const int*)d_in[1];
    const int* pmask  = (const int*)d_in[2];
    const int* pos    = (const int*)d_in[3];
    const float* pe   = (const float*)d_in[4];
    const int* imp    = (const int*)d_in[5];
    const int* idxc   = (const int*)d_in[6];
    const float* wq_w = (const float*)d_in[7];
    const float* wq_b = (const float*)d_in[8];
    const float* wk_w = (const float*)d_in[9];
    const float* wk_b = (const float*)d_in[10];
    const float* wv_w = (const float*)d_in[11];
    const float* wv_b = (const float*)d_in[12];
    const float* lsg  = (const float*)d_in[13];
    const float* lng  = (const float*)d_in[14];
    const float* lnb  = (const float*)d_in[15];
    float* out = (float*)d_out;

    size_t n = (size_t)Bb * Cc * Tt * Dd;
    short* qb = (short*)d_ws;
    short* kb = qb + n;
    short* vt = kb + n;
    short* Wb = vt + n;

    k_wconv<<<dim3(3 * Dd * Dd / 256), dim3(256), 0, stream>>>(wq_w, wk_w, wv_w, Wb);
    k_qkvm<<<dim3(Bb * Tt * Cc / 64), dim3(256), 0, stream>>>(
        x, xmask, pos, pe, imp, idxc, Wb, wq_b, wk_b, qb, kb);
    k_v<<<dim3(Tt / 64, Bb * Cc), dim3(256), 0, stream>>>(
        x, xmask, imp, idxc, Wb, wv_b, vt);
    k_attn<<<dim3(256, 8), dim3(512), 0, stream>>>(
        qb, kb, vt, x, pmask, lsg, lng, lnb, out);
}

// Round 8
// 315.991 us; speedup vs baseline: 1.8636x; 1.1233x over previous
//
#include <hip/hip_runtime.h>
#include <hip/hip_bf16.h>

#define Bb 8
#define Tt 512
#define Cc 32
#define Dd 128
#define SCALE 0.08838834764831845f
#define SROW2 264  // S chunk row stride in bf16 elems (256 + 8 pad)

typedef unsigned int u32;
typedef __hip_bfloat16 bf16;
typedef __attribute__((ext_vector_type(8))) short short8;
typedef __attribute__((ext_vector_type(4))) short short4v;
typedef __attribute__((ext_vector_type(4))) float floatx4;

__device__ __forceinline__ short f2bf(float f) {
    __hip_bfloat16 h = __float2bfloat16(f);
    return *(short*)&h;
}
__device__ __forceinline__ float bf2f(short s) {
    return __uint_as_float(((u32)(unsigned short)s) << 16);
}

// ---------------- Kernel 0: W f32 -> bf16 ----------------
__global__ __launch_bounds__(256)
void k_wconv(const float* __restrict__ wq, const float* __restrict__ wk,
             const float* __restrict__ wv, short* __restrict__ Wb)
{
    int g = blockIdx.x * 256 + threadIdx.x;
    int mat = g >> 14, rem = g & 16383;
    const float* src = (mat == 0) ? wq : (mat == 1) ? wk : wv;
    Wb[g] = f2bf(src[rem]);
}

// ---------------- Kernel 1: gather + QKV (MFMA) + rotation + q*SCALE -------
// r5-exact: block = 64 consecutive (b,t,c) rows = 2 tokens x 32 channels
// (gather stays in two 16KB token rows, L1-resident); all 3 matrices per
// pass (2 barriers/block). Proven best producer across r1/r4/r7 variants.
__global__ __launch_bounds__(256)
void k_qkvm(const float* __restrict__ x, const int* __restrict__ xm,
            const int* __restrict__ pos, const float* __restrict__ pe,
            const int* __restrict__ imp, const int* __restrict__ idxc,
            const short* __restrict__ Wb,
            const float* __restrict__ bq, const float* __restrict__ bk,
            const float* __restrict__ bv,
            short* __restrict__ qb, short* __restrict__ kb, short* __restrict__ vb)
{
    const int R0  = blockIdx.x * 64;
    const int b   = R0 >> 14;
    const int t0  = (R0 >> 5) & 511;
    const int tid = threadIdx.x;
    const int w    = tid >> 6;
    const int lane = tid & 63;
    const int quad = lane >> 4;
    const int m    = lane & 15;

    __shared__ short xg[64 * 136];
    __shared__ short ot[64 * 392];

#pragma unroll
    for (int i = 0; i < 8; ++i) {
        int u   = tid + i * 256;
        int row = u >> 5, seg = u & 31;
        int R   = R0 + row;
        int idx = xm[R] ? imp[R >> 5] : idxc[R];
        float4 v = *(const float4*)(x + ((long)(R >> 5) * Cc + idx) * Dd + seg * 4);
        short4v s = {f2bf(v.x), f2bf(v.y), f2bf(v.z), f2bf(v.w)};
        *(short4v*)&xg[row * 136 + seg * 4] = s;
    }

    short8 wf[6][4];
    float  bias_v[6];
#pragma unroll
    for (int mat = 0; mat < 3; ++mat) {
        const float* bp = (mat == 0) ? bq : (mat == 1) ? bk : bv;
#pragma unroll
        for (int h = 0; h < 2; ++h) {
            int sl = mat * 2 + h;
            int ct = h * 4 + w;
            bias_v[sl] = bp[ct * 16 + m];
#pragma unroll
            for (int kk = 0; kk < 4; ++kk)
                wf[sl][kk] = *(const short8*)(Wb + ((long)mat * 128 + ct * 16 + m) * 128
                                              + kk * 32 + quad * 8);
        }
    }
    __syncthreads();

    for (int rt = 0; rt < 4; ++rt) {
        short8 af[4];
#pragma unroll
        for (int kk = 0; kk < 4; ++kk)
            af[kk] = *(const short8*)&xg[(rt * 16 + m) * 136 + kk * 32 + quad * 8];

        floatx4 acc[6];
#pragma unroll
        for (int sl = 0; sl < 6; ++sl) acc[sl] = (floatx4){0.f, 0.f, 0.f, 0.f};
#pragma unroll
        for (int kk = 0; kk < 4; ++kk)
#pragma unroll
            for (int sl = 0; sl < 6; ++sl)
                acc[sl] = __builtin_amdgcn_mfma_f32_16x16x32_bf16(af[kk], wf[sl][kk], acc[sl], 0, 0, 0);

        int po[4];
#pragma unroll
        for (int r = 0; r < 4; ++r) po[r] = pos[R0 + rt * 16 + quad * 4 + r];

#pragma unroll
        for (int sl = 0; sl < 6; ++sl) {
            int mat = sl >> 1;
            int ct  = (sl & 1) * 4 + w;
            int d   = ct * 16 + m;
#pragma unroll
            for (int r = 0; r < 4; ++r) {
                float v = acc[sl][r] + bias_v[sl];
                float p = __shfl_xor(v, 1, 64);
                if (mat < 2) {
                    const float* rp = pe + ((long)po[r] * (Dd / 2) + (d >> 1)) * 2;
                    float r0 = rp[0], r1 = rp[1];
                    v = (d & 1) ? fmaf(p, r1, v * r0) : fmaf(v, r0, -(p * r1));
                    if (mat == 0) v *= SCALE;
                }
                ot[(rt * 16 + quad * 4 + r) * 392 + mat * 128 + d] = f2bf(v);
            }
        }
    }
    __syncthreads();

    short* const mats[3] = {qb, kb, vb};
#pragma unroll
    for (int mat = 0; mat < 3; ++mat) {
        short* dst = mats[mat];
#pragma unroll
        for (int i = 0; i < 4; ++i) {
            int g = tid + i * 256;
            int n = g >> 4, off = (g & 15) * 8;
            int c = n & 31, tl = n >> 5;
            *(short8*)(dst + (((long)(b * Cc + c) * Tt) + t0 + tl) * Dd + off) =
                *(const short8*)&ot[n * 392 + mat * 128 + off];
        }
    }
}

// ---------------- Kernel 1b: V transpose + wk fold ----------------
// r5-exact: r0 structure + XOR swizzle on the 8-elem column groups
// (bijective per row) -- fixes the 8-way transpose-read bank conflict.
__global__ __launch_bounds__(256)
void k_vt(const short* __restrict__ vb, const int* __restrict__ xm,
          short* __restrict__ vt)
{
    const int head = blockIdx.y;
    const int b    = head >> 5;
    const int c    = head & 31;
    const int t0   = blockIdx.x * 64;
    const int tid  = threadIdx.x;

    __shared__ short tile[64 * 136];
    __shared__ float wks[64];

    if (tid < 64)
        wks[tid] = xm[((long)b * Tt + t0 + tid) * Cc + c] ? (1.0f / Tt) : 1.0f;

    const short* src = vb + ((long)head * Tt + t0) * Dd;
#pragma unroll
    for (int i = 0; i < 4; ++i) {
        int u = tid + i * 256;
        int row = u >> 4, col8 = u & 15;
        int c8 = col8 ^ ((row >> 3) & 7);          // swizzled 16B slot
        *(short8*)&tile[row * 136 + c8 * 8] = *(const short8*)(src + row * Dd + col8 * 8);
    }
    __syncthreads();

    short* dst = vt + (long)head * Dd * Tt + t0;
#pragma unroll
    for (int i = 0; i < 4; ++i) {
        int u = tid + i * 256;
        int d = u >> 3, t8 = (u & 7) * 8;
        int key = u & 7;                           // == ((t8+j)>>3)&7 for j<8
        int cs = ((d >> 3) ^ key) * 8 + (d & 7);
        short8 v;
#pragma unroll
        for (int j = 0; j < 8; ++j)
            v[j] = f2bf(bf2f(tile[(t8 + j) * 136 + cs]) * wks[t8 + j]);
        *(short8*)(dst + (long)d * Tt + t8) = v;
    }
}

// ---------------- Kernel 2: TQ=64 online-softmax attention + fused LN ------
// r6's 2-chunk online-softmax body (correctness-proven) with the r6 BUG
// FIXED: __launch_bounds__(512,4), not (512,8). r6's (512,8) capped VGPR at
// 64/wave -> compiler spilled qf/oa/sc to scratch (VGPR_Count 32, FETCH
// 650MB, 410us). Under (512,4) -- the bound the proven r1 kernel compiles
// cleanly at (VGPR_Count 64) -- the online body adds only ~4 scalars.
// LDS 66.6->38.9 KB: occupancy can rise to 3-4 blocks/CU at IDENTICAL
// global traffic (same grid, same K/V/Q/x reads -- FETCH ~100MB is the
// spill control).
__global__ __launch_bounds__(512, 4)
void k_attn(const short* __restrict__ qb, const short* __restrict__ kbp,
            const short* __restrict__ vtp, const float* __restrict__ x,
            const int* __restrict__ pm,
            const float* __restrict__ lsg, const float* __restrict__ lng,
            const float* __restrict__ lnb, float* __restrict__ out)
{
    const int l    = blockIdx.y * 256 + blockIdx.x;
    const int xcd  = l & 7;
    const int sws  = l >> 3;
    const int hh   = sws & 7;
    const int tl   = (sws >> 3) & 7;
    const int gg   = sws >> 6;
    const int head = xcd + ((gg * 8 + hh) << 3);   // head % 8 == xcd
    const int b    = head >> 5;
    const int c    = head & 31;
    const int qt0  = tl * 64;
    const int tid  = threadIdx.x;
    const int w    = tid >> 6;            // 0..7
    const int lane = tid & 63;
    const int quad = lane >> 4;
    const int m    = lane & 15;

    __shared__ short S[64 * SROW2];       // 33.8 KB
    __shared__ u32   pkbits[16];
    __shared__ float rlS[64];
    __shared__ float alS[64];
    __shared__ float ps1[8][64];
    __shared__ float ps2[8][64];
    __shared__ float mrs[64][2];

    // ---- p_mask bits for all 512 tokens of this head ----
    {
        bool v = pm[((long)b * Tt + tid) * Cc + c] != 0;
        unsigned long long bal = __ballot(v);
        if (lane == 0) {
            pkbits[w * 2]     = (u32)bal;
            pkbits[w * 2 + 1] = (u32)(bal >> 32);
        }
    }

    // ---- Q A-frags: 4 q-tiles (q pre-scaled by SCALE) ----
    short8 qf[4][4];
#pragma unroll
    for (int qt = 0; qt < 4; ++qt)
#pragma unroll
        for (int kk = 0; kk < 4; ++kk)
            qf[qt][kk] = *(const short8*)(qb + ((long)head * Tt + qt0 + qt * 16 + m) * Dd
                                          + kk * 32 + quad * 8);
    __syncthreads();

    const short* vbase = vtp + (long)head * Dd * Tt + ((long)(w * 16 + m)) * Tt + quad * 8;

    floatx4 oa[4];
#pragma unroll
    for (int qt = 0; qt < 4; ++qt) oa[qt] = (floatx4){0.f, 0.f, 0.f, 0.f};

    float m_run = -1e30f, l_run = 0.f;    // online softmax state (row tid>>3)

    for (int hk = 0; hk < 2; ++hk) {
        // ---- QK^T chunk: cols hk*256 .. +255 ----
        for (int ch = 0; ch < 2; ++ch) {
            int ktl = ch * 128 + w * 16 + m;       // local col 0..255
            int kt  = hk * 256 + ktl;
            const short* kp = kbp + ((long)head * Tt + kt) * Dd + quad * 8;
            floatx4 sc[4];
#pragma unroll
            for (int qt = 0; qt < 4; ++qt) sc[qt] = (floatx4){0.f, 0.f, 0.f, 0.f};
#pragma unroll
            for (int kk = 0; kk < 4; ++kk) {
                short8 bk = *(const short8*)(kp + kk * 32);
#pragma unroll
                for (int qt = 0; qt < 4; ++qt)
                    sc[qt] = __builtin_amdgcn_mfma_f32_16x16x32_bf16(qf[qt][kk], bk, sc[qt], 0, 0, 0);
            }
            bool masked = (pkbits[kt >> 5] >> (kt & 31)) & 1;
#pragma unroll
            for (int qt = 0; qt < 4; ++qt)
#pragma unroll
                for (int r = 0; r < 4; ++r)
                    S[(qt * 16 + quad * 4 + r) * SROW2 + ktl] = f2bf(masked ? -1e30f : sc[qt][r]);
        }
        __syncthreads();

        // ---- online softmax partial: row qi = tid>>3, 8 parts of 8x4 ----
        {
            int qi = tid >> 3, part = tid & 7;
            short* rowp = &S[qi * SROW2 + part * 8];
            short8 sv[4];
#pragma unroll
            for (int j = 0; j < 4; ++j) sv[j] = *(short8*)&rowp[j * 64];
            float mx = -1e30f;
#pragma unroll
            for (int j = 0; j < 4; ++j)
#pragma unroll
                for (int e = 0; e < 8; ++e) mx = fmaxf(mx, bf2f(sv[j][e]));
            mx = fmaxf(mx, __shfl_xor(mx, 1, 64));
            mx = fmaxf(mx, __shfl_xor(mx, 2, 64));
            mx = fmaxf(mx, __shfl_xor(mx, 4, 64));
            float m_new = fmaxf(m_run, mx);
            float lsum = 0.f;
#pragma unroll
            for (int j = 0; j < 4; ++j)
#pragma unroll
                for (int e = 0; e < 8; ++e) {
                    float s = bf2f(sv[j][e]);
                    float ex = (s <= -1e29f) ? 0.f : __expf(s - m_new);
                    sv[j][e] = f2bf(ex);
                    lsum += ex;
                }
#pragma unroll
            for (int j = 0; j < 4; ++j) *(short8*)&rowp[j * 64] = sv[j];
            lsum += __shfl_xor(lsum, 1, 64);
            lsum += __shfl_xor(lsum, 2, 64);
            lsum += __shfl_xor(lsum, 4, 64);
            float al = __expf(m_run - m_new);      // ==1 when m unchanged
            l_run = l_run * al + lsum;
            m_run = m_new;
            if (part == 0) {
                alS[qi] = al;
                if (hk == 1) {
                    int t = qt0 + qi;
                    bool qmask = (pkbits[t >> 5] >> (t & 31)) & 1;
                    rlS[qi] = (l_run > 0.f && !qmask) ? 1.0f / l_run : 0.f;
                }
            }
        }
        __syncthreads();

        // ---- PV chunk: rescale oa by this chunk's alpha, then accumulate --
#pragma unroll
        for (int qt = 0; qt < 4; ++qt)
#pragma unroll
            for (int r = 0; r < 4; ++r)
                oa[qt][r] *= alS[qt * 16 + quad * 4 + r];
        for (int kv = 0; kv < 8; ++kv) {
            short8 bv = *(const short8*)(vbase + (hk * 8 + kv) * 32);
#pragma unroll
            for (int qt = 0; qt < 4; ++qt) {
                short8 ap = *(const short8*)&S[(qt * 16 + m) * SROW2 + kv * 32 + quad * 8];
                oa[qt] = __builtin_amdgcn_mfma_f32_16x16x32_bf16(ap, bv, oa[qt], 0, 0, 0);
            }
        }
        __syncthreads();   // S reused next chunk; rlS ready after hk==1
    }

    // ---- epilogue: y = x + ls*(O*rl); LN over d=128 (8-wave partials) ----
    const int d = w * 16 + m;
    const float lg = lsg[d];
    float yv[4][4];
#pragma unroll
    for (int qt = 0; qt < 4; ++qt)
#pragma unroll
        for (int r = 0; r < 4; ++r) {
            int row = qt * 16 + quad * 4 + r;
            int t = qt0 + row;
            float val = oa[qt][r] * rlS[row];
            float y = x[(((long)b * Tt + t) * Cc + c) * Dd + d] + lg * val;
            yv[qt][r] = y;
        }
#pragma unroll
    for (int qt = 0; qt < 4; ++qt)
#pragma unroll
        for (int r = 0; r < 4; ++r) {
            float a = yv[qt][r], bb = yv[qt][r] * yv[qt][r];
            a += __shfl_xor(a, 1, 64); bb += __shfl_xor(bb, 1, 64);
            a += __shfl_xor(a, 2, 64); bb += __shfl_xor(bb, 2, 64);
            a += __shfl_xor(a, 4, 64); bb += __shfl_xor(bb, 4, 64);
            a += __shfl_xor(a, 8, 64); bb += __shfl_xor(bb, 8, 64);
            if (m == 0) {
                ps1[w][qt * 16 + quad * 4 + r] = a;
                ps2[w][qt * 16 + quad * 4 + r] = bb;
            }
        }
    __syncthreads();
    if (tid < 64) {
        float a = 0.f, bb = 0.f;
#pragma unroll
        for (int wv = 0; wv < 8; ++wv) { a += ps1[wv][tid]; bb += ps2[wv][tid]; }
        float mean = a * (1.0f / Dd);
        float var  = bb * (1.0f / Dd) - mean * mean;
        mrs[tid][0] = mean;
        mrs[tid][1] = rsqrtf(var + 1e-5f);
    }
    __syncthreads();

    const float g = lng[d], be = lnb[d];
#pragma unroll
    for (int qt = 0; qt < 4; ++qt)
#pragma unroll
        for (int r = 0; r < 4; ++r) {
            int row = qt * 16 + quad * 4 + r;
            int t = qt0 + row;
            out[(((long)b * Tt + t) * Cc + c) * Dd + d] =
                (yv[qt][r] - mrs[row][0]) * mrs[row][1] * g + be;
        }
}

extern "C" void kernel_launch(void* const* d_in, const int* in_sizes, int n_in,
                              void* d_out, int out_size, void* d_ws, size_t ws_size,
                              hipStream_t stream) {
    const float* x    = (const float*)d_in[0];
    const int* xmask  = (const int*)d_in[1];
    const int* pmask  = (const int*)d_in[2];
    const int* pos    = (const int*)d_in[3];
    const float* pe   = (const float*)d_in[4];
    const int* imp    = (const int*)d_in[5];
    const int* idxc   = (const int*)d_in[6];
    const float* wq_w = (const float*)d_in[7];
    const float* wq_b = (const float*)d_in[8];
    const float* wk_w = (const float*)d_in[9];
    const float* wk_b = (const float*)d_in[10];
    const float* wv_w = (const float*)d_in[11];
    const float* wv_b = (const float*)d_in[12];
    const float* lsg  = (const float*)d_in[13];
    const float* lng  = (const float*)d_in[14];
    const float* lnb  = (const float*)d_in[15];
    float* out = (float*)d_out;

    size_t n = (size_t)Bb * Cc * Tt * Dd;
    short* qb = (short*)d_ws;
    short* kb = qb + n;
    short* vb = kb + n;
    short* vt = vb + n;
    short* Wb = vt + n;

    k_wconv<<<dim3(3 * Dd * Dd / 256), dim3(256), 0, stream>>>(wq_w, wk_w, wv_w, Wb);
    k_qkvm<<<dim3(Bb * Tt * Cc / 64), dim3(256), 0, stream>>>(
        x, xmask, pos, pe, imp, idxc, Wb, wq_b, wk_b, wv_b, qb, kb, vb);
    k_vt<<<dim3(Tt / 64, Bb * Cc), dim3(256), 0, stream>>>(vb, xmask, vt);
    k_attn<<<dim3(256, 8), dim3(512), 0, stream>>>(
        qb, kb, vt, x, pmask, lsg, lng, lnb, out);
}

// Round 9
// 306.989 us; speedup vs baseline: 1.9183x; 1.0293x over previous
//
#include <hip/hip_runtime.h>
#include <hip/hip_bf16.h>

#define Bb 8
#define Tt 512
#define Cc 32
#define Dd 128
#define SCALE 0.08838834764831845f
#define SROW 520  // S row stride in bf16 elems (512 + 8 pad, 16B-aligned)

typedef unsigned int u32;
typedef __hip_bfloat16 bf16;
typedef __attribute__((ext_vector_type(8))) short short8;
typedef __attribute__((ext_vector_type(4))) short short4v;
typedef __attribute__((ext_vector_type(4))) float floatx4;

__device__ __forceinline__ short f2bf(float f) {
    __hip_bfloat16 h = __float2bfloat16(f);
    return *(short*)&h;
}
__device__ __forceinline__ float bf2f(short s) {
    return __uint_as_float(((u32)(unsigned short)s) << 16);
}

// ---------------- Kernel 0: W f32 -> bf16 ----------------
__global__ __launch_bounds__(256)
void k_wconv(const float* __restrict__ wq, const float* __restrict__ wk,
             const float* __restrict__ wv, short* __restrict__ Wb)
{
    int g = blockIdx.x * 256 + threadIdx.x;
    int mat = g >> 14, rem = g & 16383;
    const float* src = (mat == 0) ? wq : (mat == 1) ? wk : wv;
    Wb[g] = f2bf(src[rem]);
}

// ---------------- Kernel 1: gather + QKV (MFMA) + rotation + q*SCALE -------
// r5 structure (block = 2 tokens x 32 channels, L1-resident gather) with the
// MFMA operand order SWAPPED: acc = mfma(W_frag, x_frag) -> C row = d,
// C col = token. Each lane then holds 4 CONSECUTIVE d per accumulator, so
// both elements of every RoPE complex pair are IN-LANE:
//   - 96 __shfl_xor per thread -> 0
//   - pe loads: 96 x 8B scalar -> 16 x float4
//   - pos loads: 16 -> 4 per thread
//   - ot stores: 96 x ds_write_b16 -> 24 x 8B
// Same wf/af loads, same f32 rotation math, same ot layout & writeout.
__global__ __launch_bounds__(256)
void k_qkvm(const float* __restrict__ x, const int* __restrict__ xm,
            const int* __restrict__ pos, const float* __restrict__ pe,
            const int* __restrict__ imp, const int* __restrict__ idxc,
            const short* __restrict__ Wb,
            const float* __restrict__ bq, const float* __restrict__ bk,
            const float* __restrict__ bv,
            short* __restrict__ qb, short* __restrict__ kb, short* __restrict__ vb)
{
    const int R0  = blockIdx.x * 64;
    const int b   = R0 >> 14;
    const int t0  = (R0 >> 5) & 511;
    const int tid = threadIdx.x;
    const int w    = tid >> 6;
    const int lane = tid & 63;
    const int quad = lane >> 4;
    const int m    = lane & 15;

    __shared__ short xg[64 * 136];
    __shared__ short ot[64 * 392];

#pragma unroll
    for (int i = 0; i < 8; ++i) {
        int u   = tid + i * 256;
        int row = u >> 5, seg = u & 31;
        int R   = R0 + row;
        int idx = xm[R] ? imp[R >> 5] : idxc[R];
        float4 v = *(const float4*)(x + ((long)(R >> 5) * Cc + idx) * Dd + seg * 4);
        short4v s = {f2bf(v.x), f2bf(v.y), f2bf(v.z), f2bf(v.w)};
        *(short4v*)&xg[row * 136 + seg * 4] = s;
    }

    short8 wf[6][4];
    float4 bias_v[6];
#pragma unroll
    for (int mat = 0; mat < 3; ++mat) {
        const float* bp = (mat == 0) ? bq : (mat == 1) ? bk : bv;
#pragma unroll
        for (int h = 0; h < 2; ++h) {
            int sl = mat * 2 + h;
            int ct = h * 4 + w;
            bias_v[sl] = *(const float4*)(bp + ct * 16 + quad * 4);
#pragma unroll
            for (int kk = 0; kk < 4; ++kk)
                wf[sl][kk] = *(const short8*)(Wb + ((long)mat * 128 + ct * 16 + m) * 128
                                              + kk * 32 + quad * 8);
        }
    }
    __syncthreads();

    for (int rt = 0; rt < 4; ++rt) {
        short8 af[4];
#pragma unroll
        for (int kk = 0; kk < 4; ++kk)
            af[kk] = *(const short8*)&xg[(rt * 16 + m) * 136 + kk * 32 + quad * 8];

        floatx4 acc[6];
#pragma unroll
        for (int sl = 0; sl < 6; ++sl) acc[sl] = (floatx4){0.f, 0.f, 0.f, 0.f};
#pragma unroll
        for (int kk = 0; kk < 4; ++kk)
#pragma unroll
            for (int sl = 0; sl < 6; ++sl)
                acc[sl] = __builtin_amdgcn_mfma_f32_16x16x32_bf16(wf[sl][kk], af[kk], acc[sl], 0, 0, 0);

        // this lane's token (C column m) for Q/K rotation
        int po = pos[R0 + rt * 16 + m];
        const int orow = (rt * 16 + m) * 392;

        // ---- Q, K: in-lane RoPE on consecutive-d pairs ----
#pragma unroll
        for (int sl = 0; sl < 4; ++sl) {
            int mat = sl >> 1;
            int ct  = (sl & 1) * 4 + w;
            int d0  = ct * 16 + quad * 4;
            float4 rp = *(const float4*)(pe + ((long)po * (Dd / 2) + (d0 >> 1)) * 2);
            float v0 = acc[sl][0] + bias_v[sl].x;
            float v1 = acc[sl][1] + bias_v[sl].y;
            float v2 = acc[sl][2] + bias_v[sl].z;
            float v3 = acc[sl][3] + bias_v[sl].w;
            float o0 = v0 * rp.x - v1 * rp.y;
            float o1 = v0 * rp.y + v1 * rp.x;
            float o2 = v2 * rp.z - v3 * rp.w;
            float o3 = v2 * rp.w + v3 * rp.z;
            if (mat == 0) { o0 *= SCALE; o1 *= SCALE; o2 *= SCALE; o3 *= SCALE; }
            short4v s = {f2bf(o0), f2bf(o1), f2bf(o2), f2bf(o3)};
            *(short4v*)&ot[orow + mat * 128 + d0] = s;
        }
        // ---- V: bias only ----
#pragma unroll
        for (int h = 0; h < 2; ++h) {
            int sl = 4 + h;
            int ct = h * 4 + w;
            int d0 = ct * 16 + quad * 4;
            short4v s = {f2bf(acc[sl][0] + bias_v[sl].x),
                         f2bf(acc[sl][1] + bias_v[sl].y),
                         f2bf(acc[sl][2] + bias_v[sl].z),
                         f2bf(acc[sl][3] + bias_v[sl].w)};
            *(short4v*)&ot[orow + 256 + d0] = s;
        }
    }
    __syncthreads();

    short* const mats[3] = {qb, kb, vb};
#pragma unroll
    for (int mat = 0; mat < 3; ++mat) {
        short* dst = mats[mat];
#pragma unroll
        for (int i = 0; i < 4; ++i) {
            int g = tid + i * 256;
            int n = g >> 4, off = (g & 15) * 8;
            int c = n & 31, tl = n >> 5;
            *(short8*)(dst + (((long)(b * Cc + c) * Tt) + t0 + tl) * Dd + off) =
                *(const short8*)&ot[n * 392 + mat * 128 + off];
        }
    }
}

// ---------------- Kernel 1b: V transpose + wk fold ----------------
// r5-exact: r0 structure + XOR swizzle on the 8-elem column groups
// (bijective per row) -- fixes the 8-way transpose-read bank conflict.
__global__ __launch_bounds__(256)
void k_vt(const short* __restrict__ vb, const int* __restrict__ xm,
          short* __restrict__ vt)
{
    const int head = blockIdx.y;
    const int b    = head >> 5;
    const int c    = head & 31;
    const int t0   = blockIdx.x * 64;
    const int tid  = threadIdx.x;

    __shared__ short tile[64 * 136];
    __shared__ float wks[64];

    if (tid < 64)
        wks[tid] = xm[((long)b * Tt + t0 + tid) * Cc + c] ? (1.0f / Tt) : 1.0f;

    const short* src = vb + ((long)head * Tt + t0) * Dd;
#pragma unroll
    for (int i = 0; i < 4; ++i) {
        int u = tid + i * 256;
        int row = u >> 4, col8 = u & 15;
        int c8 = col8 ^ ((row >> 3) & 7);          // swizzled 16B slot
        *(short8*)&tile[row * 136 + c8 * 8] = *(const short8*)(src + row * Dd + col8 * 8);
    }
    __syncthreads();

    short* dst = vt + (long)head * Dd * Tt + t0;
#pragma unroll
    for (int i = 0; i < 4; ++i) {
        int u = tid + i * 256;
        int d = u >> 3, t8 = (u & 7) * 8;
        int key = u & 7;                           // == ((t8+j)>>3)&7 for j<8
        int cs = ((d >> 3) ^ key) * 8 + (d & 7);
        short8 v;
#pragma unroll
        for (int j = 0; j < 8; ++j)
            v[j] = f2bf(bf2f(tile[(t8 + j) * 136 + cs]) * wks[t8 + j]);
        *(short8*)(dst + (long)d * Tt + t8) = v;
    }
}

// ---------------- Kernel 2: TQ=64, 8-wave MFMA attention + fused LN --------
// r5-exact (measured 137-141 us across five rounds): TQ=64, 2 blocks/CU,
// XCD grouping (8 heads x 8 q-tiles per XCD -> 2MB L2 window, FETCH ~100MB),
// conflict-free interleaved softmax. Macro-structure experiments closed:
// TQ=32 (r2) 2x traffic; reg-prefetch (r3) spilled; online-softmax (r6 spill,
// r8 clean) slower even at 39KB LDS -- occupancy is not the limiter.
__global__ __launch_bounds__(512, 4)
void k_attn(const short* __restrict__ qb, const short* __restrict__ kbp,
            const short* __restrict__ vtp, const float* __restrict__ x,
            const int* __restrict__ pm,
            const float* __restrict__ lsg, const float* __restrict__ lng,
            const float* __restrict__ lnb, float* __restrict__ out)
{
    const int l    = blockIdx.y * 256 + blockIdx.x;
    const int xcd  = l & 7;
    const int sws  = l >> 3;
    const int hh   = sws & 7;
    const int tl   = (sws >> 3) & 7;
    const int gg   = sws >> 6;
    const int head = xcd + ((gg * 8 + hh) << 3);   // head % 8 == xcd
    const int b    = head >> 5;
    const int c    = head & 31;
    const int qt0  = tl * 64;
    const int tid  = threadIdx.x;
    const int w    = tid >> 6;            // 0..7
    const int lane = tid & 63;
    const int quad = lane >> 4;
    const int m    = lane & 15;

    __shared__ short S[64 * SROW];        // 66.6 KB
    __shared__ u32   pkbits[16];
    __shared__ float rlS[64];
    __shared__ float ps1[8][64];
    __shared__ float ps2[8][64];
    __shared__ float mrs[64][2];

    // ---- p_mask bits for all 512 tokens of this head ----
    {
        bool v = pm[((long)b * Tt + tid) * Cc + c] != 0;
        unsigned long long bal = __ballot(v);
        if (lane == 0) {
            pkbits[w * 2]     = (u32)bal;
            pkbits[w * 2 + 1] = (u32)(bal >> 32);
        }
    }

    // ---- Q A-frags: 4 q-tiles (q pre-scaled by SCALE) ----
    short8 qf[4][4];
#pragma unroll
    for (int qt = 0; qt < 4; ++qt)
#pragma unroll
        for (int kk = 0; kk < 4; ++kk)
            qf[qt][kk] = *(const short8*)(qb + ((long)head * Tt + qt0 + qt * 16 + m) * Dd
                                          + kk * 32 + quad * 8);
    __syncthreads();

    // ---- QK^T: each wave owns k-strip w*16 within 128-chunks ----
    for (int ch = 0; ch < 4; ++ch) {
        int kt = ch * 128 + w * 16 + m;
        const short* kp = kbp + ((long)head * Tt + kt) * Dd + quad * 8;
        floatx4 sc[4];
#pragma unroll
        for (int qt = 0; qt < 4; ++qt) sc[qt] = (floatx4){0.f, 0.f, 0.f, 0.f};
#pragma unroll
        for (int kk = 0; kk < 4; ++kk) {
            short8 bk = *(const short8*)(kp + kk * 32);
#pragma unroll
            for (int qt = 0; qt < 4; ++qt)
                sc[qt] = __builtin_amdgcn_mfma_f32_16x16x32_bf16(qf[qt][kk], bk, sc[qt], 0, 0, 0);
        }
        bool masked = (pkbits[kt >> 5] >> (kt & 31)) & 1;
#pragma unroll
        for (int qt = 0; qt < 4; ++qt)
#pragma unroll
            for (int r = 0; r < 4; ++r)
                S[(qt * 16 + quad * 4 + r) * SROW + kt] = f2bf(masked ? -1e30f : sc[qt][r]);
    }
    __syncthreads();

    // ---- softmax: row qi = tid>>3; lane covers cols part*8 + j*64 + e ----
    // (interleaved 8-elem blocks: 128B part-stride was an 8-way bank
    //  conflict; this mapping spreads each phase over all 32 banks.)
    {
        int qi = tid >> 3, part = tid & 7;
        short* rowp = &S[qi * SROW + part * 8];
        short8 sv[8];
#pragma unroll
        for (int j = 0; j < 8; ++j) sv[j] = *(short8*)&rowp[j * 64];
        float mx = -1e30f;
#pragma unroll
        for (int j = 0; j < 8; ++j)
#pragma unroll
            for (int e = 0; e < 8; ++e) mx = fmaxf(mx, bf2f(sv[j][e]));
        mx = fmaxf(mx, __shfl_xor(mx, 1, 64));
        mx = fmaxf(mx, __shfl_xor(mx, 2, 64));
        mx = fmaxf(mx, __shfl_xor(mx, 4, 64));
        float lsum = 0.f;
#pragma unroll
        for (int j = 0; j < 8; ++j)
#pragma unroll
            for (int e = 0; e < 8; ++e) {
                float s = bf2f(sv[j][e]);
                float ex = (s <= -1e29f) ? 0.f : __expf(s - mx);
                sv[j][e] = f2bf(ex);
                lsum += ex;
            }
#pragma unroll
        for (int j = 0; j < 8; ++j) *(short8*)&rowp[j * 64] = sv[j];
        lsum += __shfl_xor(lsum, 1, 64);
        lsum += __shfl_xor(lsum, 2, 64);
        lsum += __shfl_xor(lsum, 4, 64);
        if (part == 0) {
            int t = qt0 + qi;
            bool qmask = (pkbits[t >> 5] >> (t & 31)) & 1;
            rlS[qi] = (lsum > 0.f && !qmask) ? 1.0f / lsum : 0.f;
        }
    }
    __syncthreads();

    // ---- PV: wave owns d-strip w*16..+15; B-frags from Vt global ----
    floatx4 oa[4];
#pragma unroll
    for (int qt = 0; qt < 4; ++qt) oa[qt] = (floatx4){0.f, 0.f, 0.f, 0.f};

    const short* vbase = vtp + (long)head * Dd * Tt + ((long)(w * 16 + m)) * Tt + quad * 8;
    for (int kv = 0; kv < 16; ++kv) {
        short8 bv = *(const short8*)(vbase + kv * 32);
#pragma unroll
        for (int qt = 0; qt < 4; ++qt) {
            short8 ap = *(const short8*)&S[(qt * 16 + m) * SROW + kv * 32 + quad * 8];
            oa[qt] = __builtin_amdgcn_mfma_f32_16x16x32_bf16(ap, bv, oa[qt], 0, 0, 0);
        }
    }

    // ---- epilogue: y = x + ls*(O*rl); LN over d=128 (8-wave partials) ----
    const int d = w * 16 + m;
    const float lg = lsg[d];
    float yv[4][4];
    float s1[4][4], s2[4][4];
#pragma unroll
    for (int qt = 0; qt < 4; ++qt)
#pragma unroll
        for (int r = 0; r < 4; ++r) {
            int row = qt * 16 + quad * 4 + r;
            int t = qt0 + row;
            float val = oa[qt][r] * rlS[row];
            float y = x[(((long)b * Tt + t) * Cc + c) * Dd + d] + lg * val;
            yv[qt][r] = y;
            s1[qt][r] = y;
            s2[qt][r] = y * y;
        }
#pragma unroll
    for (int qt = 0; qt < 4; ++qt)
#pragma unroll
        for (int r = 0; r < 4; ++r) {
            float a = s1[qt][r], bb = s2[qt][r];
            a += __shfl_xor(a, 1, 64); bb += __shfl_xor(bb, 1, 64);
            a += __shfl_xor(a, 2, 64); bb += __shfl_xor(bb, 2, 64);
            a += __shfl_xor(a, 4, 64); bb += __shfl_xor(bb, 4, 64);
            a += __shfl_xor(a, 8, 64); bb += __shfl_xor(bb, 8, 64);
            if (m == 0) {
                ps1[w][qt * 16 + quad * 4 + r] = a;
                ps2[w][qt * 16 + quad * 4 + r] = bb;
            }
        }
    __syncthreads();
    if (tid < 64) {
        float a = 0.f, bb = 0.f;
#pragma unroll
        for (int wv = 0; wv < 8; ++wv) { a += ps1[wv][tid]; bb += ps2[wv][tid]; }
        float mean = a * (1.0f / Dd);
        float var  = bb * (1.0f / Dd) - mean * mean;
        mrs[tid][0] = mean;
        mrs[tid][1] = rsqrtf(var + 1e-5f);
    }
    __syncthreads();

    const float g = lng[d], be = lnb[d];
#pragma unroll
    for (int qt = 0; qt < 4; ++qt)
#pragma unroll
        for (int r = 0; r < 4; ++r) {
            int row = qt * 16 + quad * 4 + r;
            int t = qt0 + row;
            out[(((long)b * Tt + t) * Cc + c) * Dd + d] =
                (yv[qt][r] - mrs[row][0]) * mrs[row][1] * g + be;
        }
}

extern "C" void kernel_launch(void* const* d_in, const int* in_sizes, int n_in,
                              void* d_out, int out_size, void* d_ws, size_t ws_size,
                              hipStream_t stream) {
    const float* x    = (const float*)d_in[0];
    const int* xmask  = (const int*)d_in[1];
    const int* pmask  = (const int*)d_in[2];
    const int* pos    = (const int*)d_in[3];
    const float* pe   = (const float*)d_in[4];
    const int* imp    = (const int*)d_in[5];
    const int* idxc   = (const int*)d_in[6];
    const float* wq_w = (const float*)d_in[7];
    const float* wq_b = (const float*)d_in[8];
    const float* wk_w = (const float*)d_in[9];
    const float* wk_b = (const float*)d_in[10];
    const float* wv_w = (const float*)d_in[11];
    const float* wv_b = (const float*)d_in[12];
    const float* lsg  = (const float*)d_in[13];
    const float* lng  = (const float*)d_in[14];
    const float* lnb  = (const float*)d_in[15];
    float* out = (float*)d_out;

    size_t n = (size_t)Bb * Cc * Tt * Dd;
    short* qb = (short*)d_ws;
    short* kb = qb + n;
    short* vb = kb + n;
    short* vt = vb + n;
    short* Wb = vt + n;

    k_wconv<<<dim3(3 * Dd * Dd / 256), dim3(256), 0, stream>>>(wq_w, wk_w, wv_w, Wb);
    k_qkvm<<<dim3(Bb * Tt * Cc / 64), dim3(256), 0, stream>>>(
        x, xmask, pos, pe, imp, idxc, Wb, wq_b, wk_b, wv_b, qb, kb, vb);
    k_vt<<<dim3(Tt / 64, Bb * Cc), dim3(256), 0, stream>>>(vb, xmask, vt);
    k_attn<<<dim3(256, 8), dim3(512), 0, stream>>>(
        qb, kb, vt, x, pmask, lsg, lng, lnb, out);
}

// Round 11
// 302.558 us; speedup vs baseline: 1.9464x; 1.0146x over previous
//
#include <hip/hip_runtime.h>
#include <hip/hip_bf16.h>

#define Bb 8
#define Tt 512
#define Cc 32
#define Dd 128
#define SCALE 0.08838834764831845f
#define SROW 520  // S row stride in bf16 elems (512 + 8 pad, 16B-aligned)

typedef unsigned int u32;
typedef __hip_bfloat16 bf16;
typedef __attribute__((ext_vector_type(8))) short short8;
typedef __attribute__((ext_vector_type(4))) short short4v;
typedef __attribute__((ext_vector_type(4))) float floatx4;

__device__ __forceinline__ short f2bf(float f) {
    __hip_bfloat16 h = __float2bfloat16(f);
    return *(short*)&h;
}
__device__ __forceinline__ float bf2f(short s) {
    return __uint_as_float(((u32)(unsigned short)s) << 16);
}

// ---------------- Kernel 0: W f32 -> bf16 ----------------
__global__ __launch_bounds__(256)
void k_wconv(const float* __restrict__ wq, const float* __restrict__ wk,
             const float* __restrict__ wv, short* __restrict__ Wb)
{
    int g = blockIdx.x * 256 + threadIdx.x;
    int mat = g >> 14, rem = g & 16383;
    const float* src = (mat == 0) ? wq : (mat == 1) ? wk : wv;
    Wb[g] = f2bf(src[rem]);
}

// ---------------- Kernel 1: gather + QKV (MFMA) + rotation + q*SCALE -------
// r9-exact (passed, best measured): 2 tokens x 32 channels block,
// swapped-operand MFMA (C row = d) -> in-lane RoPE, zero shuffles,
// vectorized pe/bias/ot.
__global__ __launch_bounds__(256)
void k_qkvm(const float* __restrict__ x, const int* __restrict__ xm,
            const int* __restrict__ pos, const float* __restrict__ pe,
            const int* __restrict__ imp, const int* __restrict__ idxc,
            const short* __restrict__ Wb,
            const float* __restrict__ bq, const float* __restrict__ bk,
            const float* __restrict__ bv,
            short* __restrict__ qb, short* __restrict__ kb, short* __restrict__ vb)
{
    const int R0  = blockIdx.x * 64;
    const int b   = R0 >> 14;
    const int t0  = (R0 >> 5) & 511;
    const int tid = threadIdx.x;
    const int w    = tid >> 6;
    const int lane = tid & 63;
    const int quad = lane >> 4;
    const int m    = lane & 15;

    __shared__ short xg[64 * 136];
    __shared__ short ot[64 * 392];

#pragma unroll
    for (int i = 0; i < 8; ++i) {
        int u   = tid + i * 256;
        int row = u >> 5, seg = u & 31;
        int R   = R0 + row;
        int idx = xm[R] ? imp[R >> 5] : idxc[R];
        float4 v = *(const float4*)(x + ((long)(R >> 5) * Cc + idx) * Dd + seg * 4);
        short4v s = {f2bf(v.x), f2bf(v.y), f2bf(v.z), f2bf(v.w)};
        *(short4v*)&xg[row * 136 + seg * 4] = s;
    }

    short8 wf[6][4];
    float4 bias_v[6];
#pragma unroll
    for (int mat = 0; mat < 3; ++mat) {
        const float* bp = (mat == 0) ? bq : (mat == 1) ? bk : bv;
#pragma unroll
        for (int h = 0; h < 2; ++h) {
            int sl = mat * 2 + h;
            int ct = h * 4 + w;
            bias_v[sl] = *(const float4*)(bp + ct * 16 + quad * 4);
#pragma unroll
            for (int kk = 0; kk < 4; ++kk)
                wf[sl][kk] = *(const short8*)(Wb + ((long)mat * 128 + ct * 16 + m) * 128
                                              + kk * 32 + quad * 8);
        }
    }
    __syncthreads();

    for (int rt = 0; rt < 4; ++rt) {
        short8 af[4];
#pragma unroll
        for (int kk = 0; kk < 4; ++kk)
            af[kk] = *(const short8*)&xg[(rt * 16 + m) * 136 + kk * 32 + quad * 8];

        floatx4 acc[6];
#pragma unroll
        for (int sl = 0; sl < 6; ++sl) acc[sl] = (floatx4){0.f, 0.f, 0.f, 0.f};
#pragma unroll
        for (int kk = 0; kk < 4; ++kk)
#pragma unroll
            for (int sl = 0; sl < 6; ++sl)
                acc[sl] = __builtin_amdgcn_mfma_f32_16x16x32_bf16(wf[sl][kk], af[kk], acc[sl], 0, 0, 0);

        // this lane's token (C column m) for Q/K rotation
        int po = pos[R0 + rt * 16 + m];
        const int orow = (rt * 16 + m) * 392;

        // ---- Q, K: in-lane RoPE on consecutive-d pairs ----
#pragma unroll
        for (int sl = 0; sl < 4; ++sl) {
            int mat = sl >> 1;
            int ct  = (sl & 1) * 4 + w;
            int d0  = ct * 16 + quad * 4;
            float4 rp = *(const float4*)(pe + ((long)po * (Dd / 2) + (d0 >> 1)) * 2);
            float v0 = acc[sl][0] + bias_v[sl].x;
            float v1 = acc[sl][1] + bias_v[sl].y;
            float v2 = acc[sl][2] + bias_v[sl].z;
            float v3 = acc[sl][3] + bias_v[sl].w;
            float o0 = v0 * rp.x - v1 * rp.y;
            float o1 = v0 * rp.y + v1 * rp.x;
            float o2 = v2 * rp.z - v3 * rp.w;
            float o3 = v2 * rp.w + v3 * rp.z;
            if (mat == 0) { o0 *= SCALE; o1 *= SCALE; o2 *= SCALE; o3 *= SCALE; }
            short4v s = {f2bf(o0), f2bf(o1), f2bf(o2), f2bf(o3)};
            *(short4v*)&ot[orow + mat * 128 + d0] = s;
        }
        // ---- V: bias only ----
#pragma unroll
        for (int h = 0; h < 2; ++h) {
            int sl = 4 + h;
            int ct = h * 4 + w;
            int d0 = ct * 16 + quad * 4;
            short4v s = {f2bf(acc[sl][0] + bias_v[sl].x),
                         f2bf(acc[sl][1] + bias_v[sl].y),
                         f2bf(acc[sl][2] + bias_v[sl].z),
                         f2bf(acc[sl][3] + bias_v[sl].w)};
            *(short4v*)&ot[orow + 256 + d0] = s;
        }
    }
    __syncthreads();

    short* const mats[3] = {qb, kb, vb};
#pragma unroll
    for (int mat = 0; mat < 3; ++mat) {
        short* dst = mats[mat];
#pragma unroll
        for (int i = 0; i < 4; ++i) {
            int g = tid + i * 256;
            int n = g >> 4, off = (g & 15) * 8;
            int c = n & 31, tl = n >> 5;
            *(short8*)(dst + (((long)(b * Cc + c) * Tt) + t0 + tl) * Dd + off) =
                *(const short8*)&ot[n * 392 + mat * 128 + off];
        }
    }
}

// ---------------- Kernel 1b: V transpose + wk fold ----------------
// r5-exact: r0 structure + XOR swizzle on the 8-elem column groups
// (bijective per row) -- fixes the 8-way transpose-read bank conflict.
__global__ __launch_bounds__(256)
void k_vt(const short* __restrict__ vb, const int* __restrict__ xm,
          short* __restrict__ vt)
{
    const int head = blockIdx.y;
    const int b    = head >> 5;
    const int c    = head & 31;
    const int t0   = blockIdx.x * 64;
    const int tid  = threadIdx.x;

    __shared__ short tile[64 * 136];
    __shared__ float wks[64];

    if (tid < 64)
        wks[tid] = xm[((long)b * Tt + t0 + tid) * Cc + c] ? (1.0f / Tt) : 1.0f;

    const short* src = vb + ((long)head * Tt + t0) * Dd;
#pragma unroll
    for (int i = 0; i < 4; ++i) {
        int u = tid + i * 256;
        int row = u >> 4, col8 = u & 15;
        int c8 = col8 ^ ((row >> 3) & 7);          // swizzled 16B slot
        *(short8*)&tile[row * 136 + c8 * 8] = *(const short8*)(src + row * Dd + col8 * 8);
    }
    __syncthreads();

    short* dst = vt + (long)head * Dd * Tt + t0;
#pragma unroll
    for (int i = 0; i < 4; ++i) {
        int u = tid + i * 256;
        int d = u >> 3, t8 = (u & 7) * 8;
        int key = u & 7;                           // == ((t8+j)>>3)&7 for j<8
        int cs = ((d >> 3) ^ key) * 8 + (d & 7);
        short8 v;
#pragma unroll
        for (int j = 0; j < 8; ++j)
            v[j] = f2bf(bf2f(tile[(t8 + j) * 136 + cs]) * wks[t8 + j]);
        *(short8*)(dst + (long)d * Tt + t8) = v;
    }
}

// ---------------- Kernel 2: TQ=64, 8-wave MFMA attention + fused LN --------
// r5 macro-structure with ONE change: QK^T operand swap only.
//  - QK^T: mfma(k_frag, q_frag) -> C row = k: lane holds 4 consecutive k
//    for one q row -> S store = 16 x 8B writes (was 64 x ds_write_b16).
//    S layout/content identical to r5 (scores[q][k], each cell once).
//  - softmax, PV, epilogue: r5-EXACT (the r10 float4 epilogue caused an
//    O(1) run-varying failure; ls_gamma=1e-5 attenuation proves the fault
//    was in the x/LN/store half, so that half stays on proven code).
__global__ __launch_bounds__(512, 4)
void k_attn(const short* __restrict__ qb, const short* __restrict__ kbp,
            const short* __restrict__ vtp, const float* __restrict__ x,
            const int* __restrict__ pm,
            const float* __restrict__ lsg, const float* __restrict__ lng,
            const float* __restrict__ lnb, float* __restrict__ out)
{
    const int l    = blockIdx.y * 256 + blockIdx.x;
    const int xcd  = l & 7;
    const int sws  = l >> 3;
    const int hh   = sws & 7;
    const int tl   = (sws >> 3) & 7;
    const int gg   = sws >> 6;
    const int head = xcd + ((gg * 8 + hh) << 3);   // head % 8 == xcd
    const int b    = head >> 5;
    const int c    = head & 31;
    const int qt0  = tl * 64;
    const int tid  = threadIdx.x;
    const int w    = tid >> 6;            // 0..7
    const int lane = tid & 63;
    const int quad = lane >> 4;
    const int m    = lane & 15;

    __shared__ short S[64 * SROW];        // 66.6 KB
    __shared__ u32   pkbits[16];
    __shared__ float rlS[64];
    __shared__ float ps1[8][64];
    __shared__ float ps2[8][64];
    __shared__ float mrs[64][2];

    // ---- p_mask bits for all 512 tokens of this head ----
    {
        bool v = pm[((long)b * Tt + tid) * Cc + c] != 0;
        unsigned long long bal = __ballot(v);
        if (lane == 0) {
            pkbits[w * 2]     = (u32)bal;
            pkbits[w * 2 + 1] = (u32)(bal >> 32);
        }
    }

    // ---- Q A-frags: 4 q-tiles (q pre-scaled by SCALE) ----
    short8 qf[4][4];
#pragma unroll
    for (int qt = 0; qt < 4; ++qt)
#pragma unroll
        for (int kk = 0; kk < 4; ++kk)
            qf[qt][kk] = *(const short8*)(qb + ((long)head * Tt + qt0 + qt * 16 + m) * Dd
                                          + kk * 32 + quad * 8);
    __syncthreads();

    // ---- QK^T (swapped): C = K.Q^T; lane writes 4 consecutive k at
    //      row q = qt*16+m ----
    for (int ch = 0; ch < 4; ++ch) {
        int kt = ch * 128 + w * 16 + m;              // A-frag row = m
        const short* kp = kbp + ((long)head * Tt + kt) * Dd + quad * 8;
        floatx4 sc[4];
#pragma unroll
        for (int qt = 0; qt < 4; ++qt) sc[qt] = (floatx4){0.f, 0.f, 0.f, 0.f};
#pragma unroll
        for (int kk = 0; kk < 4; ++kk) {
            short8 ak = *(const short8*)(kp + kk * 32);
#pragma unroll
            for (int qt = 0; qt < 4; ++qt)
                sc[qt] = __builtin_amdgcn_mfma_f32_16x16x32_bf16(ak, qf[qt][kk], sc[qt], 0, 0, 0);
        }
        int k0 = ch * 128 + w * 16 + quad * 4;       // C row base = k
#pragma unroll
        for (int qt = 0; qt < 4; ++qt) {
            short4v s;
#pragma unroll
            for (int r = 0; r < 4; ++r) {
                int k = k0 + r;
                bool masked = (pkbits[k >> 5] >> (k & 31)) & 1;
                s[r] = f2bf(masked ? -1e30f : sc[qt][r]);
            }
            *(short4v*)&S[(qt * 16 + m) * SROW + k0] = s;
        }
    }
    __syncthreads();

    // ---- softmax: row qi = tid>>3; lane covers cols part*8 + j*64 + e ----
    // (r5-exact)
    {
        int qi = tid >> 3, part = tid & 7;
        short* rowp = &S[qi * SROW + part * 8];
        short8 sv[8];
#pragma unroll
        for (int j = 0; j < 8; ++j) sv[j] = *(short8*)&rowp[j * 64];
        float mx = -1e30f;
#pragma unroll
        for (int j = 0; j < 8; ++j)
#pragma unroll
            for (int e = 0; e < 8; ++e) mx = fmaxf(mx, bf2f(sv[j][e]));
        mx = fmaxf(mx, __shfl_xor(mx, 1, 64));
        mx = fmaxf(mx, __shfl_xor(mx, 2, 64));
        mx = fmaxf(mx, __shfl_xor(mx, 4, 64));
        float lsum = 0.f;
#pragma unroll
        for (int j = 0; j < 8; ++j)
#pragma unroll
            for (int e = 0; e < 8; ++e) {
                float s = bf2f(sv[j][e]);
                float ex = (s <= -1e29f) ? 0.f : __expf(s - mx);
                sv[j][e] = f2bf(ex);
                lsum += ex;
            }
#pragma unroll
        for (int j = 0; j < 8; ++j) *(short8*)&rowp[j * 64] = sv[j];
        lsum += __shfl_xor(lsum, 1, 64);
        lsum += __shfl_xor(lsum, 2, 64);
        lsum += __shfl_xor(lsum, 4, 64);
        if (part == 0) {
            int t = qt0 + qi;
            bool qmask = (pkbits[t >> 5] >> (t & 31)) & 1;
            rlS[qi] = (lsum > 0.f && !qmask) ? 1.0f / lsum : 0.f;
        }
    }
    __syncthreads();

    // ---- PV: r5-exact (wave owns d-strip w*16..+15) ----
    floatx4 oa[4];
#pragma unroll
    for (int qt = 0; qt < 4; ++qt) oa[qt] = (floatx4){0.f, 0.f, 0.f, 0.f};

    const short* vbase = vtp + (long)head * Dd * Tt + ((long)(w * 16 + m)) * Tt + quad * 8;
    for (int kv = 0; kv < 16; ++kv) {
        short8 bv = *(const short8*)(vbase + kv * 32);
#pragma unroll
        for (int qt = 0; qt < 4; ++qt) {
            short8 ap = *(const short8*)&S[(qt * 16 + m) * SROW + kv * 32 + quad * 8];
            oa[qt] = __builtin_amdgcn_mfma_f32_16x16x32_bf16(ap, bv, oa[qt], 0, 0, 0);
        }
    }

    // ---- epilogue: r5-exact ----
    const int d = w * 16 + m;
    const float lg = lsg[d];
    float yv[4][4];
    float s1[4][4], s2[4][4];
#pragma unroll
    for (int qt = 0; qt < 4; ++qt)
#pragma unroll
        for (int r = 0; r < 4; ++r) {
            int row = qt * 16 + quad * 4 + r;
            int t = qt0 + row;
            float val = oa[qt][r] * rlS[row];
            float y = x[(((long)b * Tt + t) * Cc + c) * Dd + d] + lg * val;
            yv[qt][r] = y;
            s1[qt][r] = y;
            s2[qt][r] = y * y;
        }
#pragma unroll
    for (int qt = 0; qt < 4; ++qt)
#pragma unroll
        for (int r = 0; r < 4; ++r) {
            float a = s1[qt][r], bb = s2[qt][r];
            a += __shfl_xor(a, 1, 64); bb += __shfl_xor(bb, 1, 64);
            a += __shfl_xor(a, 2, 64); bb += __shfl_xor(bb, 2, 64);
            a += __shfl_xor(a, 4, 64); bb += __shfl_xor(bb, 4, 64);
            a += __shfl_xor(a, 8, 64); bb += __shfl_xor(bb, 8, 64);
            if (m == 0) {
                ps1[w][qt * 16 + quad * 4 + r] = a;
                ps2[w][qt * 16 + quad * 4 + r] = bb;
            }
        }
    __syncthreads();
    if (tid < 64) {
        float a = 0.f, bb = 0.f;
#pragma unroll
        for (int wv = 0; wv < 8; ++wv) { a += ps1[wv][tid]; bb += ps2[wv][tid]; }
        float mean = a * (1.0f / Dd);
        float var  = bb * (1.0f / Dd) - mean * mean;
        mrs[tid][0] = mean;
        mrs[tid][1] = rsqrtf(var + 1e-5f);
    }
    __syncthreads();

    const float g = lng[d], be = lnb[d];
#pragma unroll
    for (int qt = 0; qt < 4; ++qt)
#pragma unroll
        for (int r = 0; r < 4; ++r) {
            int row = qt * 16 + quad * 4 + r;
            int t = qt0 + row;
            out[(((long)b * Tt + t) * Cc + c) * Dd + d] =
                (yv[qt][r] - mrs[row][0]) * mrs[row][1] * g + be;
        }
}

extern "C" void kernel_launch(void* const* d_in, const int* in_sizes, int n_in,
                              void* d_out, int out_size, void* d_ws, size_t ws_size,
                              hipStream_t stream) {
    const float* x    = (const float*)d_in[0];
    const int* xmask  = (const int*)d_in[1];
    const int* pmask  = (const int*)d_in[2];
    const int* pos    = (const int*)d_in[3];
    const float* pe   = (const float*)d_in[4];
    const int* imp    = (const int*)d_in[5];
    const int* idxc   = (const int*)d_in[6];
    const float* wq_w = (const float*)d_in[7];
    const float* wq_b = (const float*)d_in[8];
    const float* wk_w = (const float*)d_in[9];
    const float* wk_b = (const float*)d_in[10];
    const float* wv_w = (const float*)d_in[11];
    const float* wv_b = (const float*)d_in[12];
    const float* lsg  = (const float*)d_in[13];
    const float* lng  = (const float*)d_in[14];
    const float* lnb  = (const float*)d_in[15];
    float* out = (float*)d_out;

    size_t n = (size_t)Bb * Cc * Tt * Dd;
    short* qb = (short*)d_ws;
    short* kb = qb + n;
    short* vb = kb + n;
    short* vt = vb + n;
    short* Wb = vt + n;

    k_wconv<<<dim3(3 * Dd * Dd / 256), dim3(256), 0, stream>>>(wq_w, wk_w, wv_w, Wb);
    k_qkvm<<<dim3(Bb * Tt * Cc / 64), dim3(256), 0, stream>>>(
        x, xmask, pos, pe, imp, idxc, Wb, wq_b, wk_b, wv_b, qb, kb, vb);
    k_vt<<<dim3(Tt / 64, Bb * Cc), dim3(256), 0, stream>>>(vb, xmask, vt);
    k_attn<<<dim3(256, 8), dim3(512), 0, stream>>>(
        qb, kb, vt, x, pmask, lsg, lng, lnb, out);
}